// Round 4
// baseline (322.297 us; speedup 1.0000x reference)
//
#include <hip/hip_runtime.h>

// Gate-level FP8 E4M3 adder circuit, replayed as integer bit ops.
// Each row = 8 float32 "bits" (sign | exp4 | man3, MSB first), values in {0.0,1.0}.
// 1.0f == 0x3F800000 -> bit = (u >> 23) & 1. Output bit b -> b ? 0x3F800000 : 0.
//
// R3: branch-free fast-path kernel (no divergent bounds checks -> compiler can
// keep all 16 dwordx4 loads in flight; R2's VGPR_Count=36 proved loads were
// sunk to uses under the valid[k] exec-mask). Plain loads (L1 serves the
// paired stride-2 halves, L3 keeps ~50% input hits), nt stores (streaming).

typedef unsigned int uint32x4 __attribute__((ext_vector_type(4)));

__device__ __forceinline__ unsigned bit_of(unsigned u) { return (u >> 23) & 1u; }
__device__ __forceinline__ unsigned f_of(unsigned b)   { return b ? 0x3F800000u : 0u; }

__device__ __forceinline__ void fp8_add_row(const uint32x4& a0, const uint32x4& a1,
                                            const uint32x4& b0, const uint32x4& b1,
                                            uint32x4& o0, uint32x4& o1)
{
    unsigned sa = bit_of(a0.x);
    unsigned ea = (bit_of(a0.y) << 3) | (bit_of(a0.z) << 2) | (bit_of(a0.w) << 1) | bit_of(a1.x);
    unsigned ma = (bit_of(a1.y) << 2) | (bit_of(a1.z) << 1) | bit_of(a1.w);
    unsigned sb = bit_of(b0.x);
    unsigned eb = (bit_of(b0.y) << 3) | (bit_of(b0.z) << 2) | (bit_of(b0.w) << 1) | bit_of(b1.x);
    unsigned mb = (bit_of(b1.y) << 2) | (bit_of(b1.z) << 1) | bit_of(b1.w);

    // comparator4 + OR(gt,eq): sel = (ea >= eb)
    unsigned sel = (ea >= eb) ? 1u : 0u;
    unsigned exp_l = sel ? ea : eb, exp_s = sel ? eb : ea;
    unsigned man_l = sel ? ma : mb, man_s = sel ? mb : ma;
    unsigned sign_l = sel ? sa : sb, sign_s = sel ? sb : sa;

    unsigned diff = (exp_l - exp_s) & 0xFu;        // 4-bit subtract, exact (l >= s)
    unsigned hid_l = exp_l ? 1u : 0u;
    unsigned hid_s = exp_s ? 1u : 0u;

    // 12-bit extended mantissas, MSB-first bit 11..0: [0, hid, man(3), 0*7]
    unsigned ext_l = (hid_l << 10) | (man_l << 7);
    unsigned ext_s = ((hid_s << 10) | (man_s << 7)) >> diff;

    unsigned same_sign = (sign_l == sign_s);
    // 12-bit ripple add/sub both wrap mod 4096 (carry/borrow-out dropped)
    unsigned mant = same_sign ? ((ext_l + ext_s) & 0xFFFu)
                              : ((ext_l - ext_s) & 0xFFFu);

    unsigned top8 = mant >> 4;                     // mant bits 11..4
    unsigned lzc = top8 ? (unsigned)(__clz((int)top8) - 24) : 7u;  // lzd8 -> 7 on zero
    unsigned norm = (top8 << lzc) & 0xFFu;         // barrel_left8

    unsigned exp_new = (exp_l - lzc + 1u) & 0xFu;  // subtract_bits + increment4, mod 16
    unsigned man_out = (norm >> 4) & 0x7u;         // norm[1:4] = bits 6..4

    o0.x = f_of(sign_l);
    o0.y = f_of((exp_new >> 3) & 1u);
    o0.z = f_of((exp_new >> 2) & 1u);
    o0.w = f_of((exp_new >> 1) & 1u);
    o1.x = f_of(exp_new & 1u);
    o1.y = f_of((man_out >> 2) & 1u);
    o1.z = f_of((man_out >> 1) & 1u);
    o1.w = f_of(man_out & 1u);
}

constexpr int RPT = 4;
constexpr int BLOCK = 256;
constexpr int ROWS_PER_BLOCK = BLOCK * RPT;

// Fast path: every row index in range by construction — zero control flow,
// all 16 loads issue back-to-back before any compute.
__global__ __launch_bounds__(BLOCK) void fp8_adder_fast(
    const uint32x4* __restrict__ A, const uint32x4* __restrict__ B,
    uint32x4* __restrict__ O)
{
    int base = blockIdx.x * ROWS_PER_BLOCK + threadIdx.x;

    uint32x4 a0[RPT], a1[RPT], b0[RPT], b1[RPT];
    #pragma unroll
    for (int k = 0; k < RPT; ++k) {
        int i = base + k * BLOCK;
        a0[k] = A[2 * i];
        a1[k] = A[2 * i + 1];
        b0[k] = B[2 * i];
        b1[k] = B[2 * i + 1];
    }

    #pragma unroll
    for (int k = 0; k < RPT; ++k) {
        int i = base + k * BLOCK;
        uint32x4 o0, o1;
        fp8_add_row(a0[k], a1[k], b0[k], b1[k], o0, o1);
        __builtin_nontemporal_store(o0, &O[2 * i]);
        __builtin_nontemporal_store(o1, &O[2 * i + 1]);
    }
}

// Tail: bounds-checked, one row per thread.
__global__ __launch_bounds__(BLOCK) void fp8_adder_tail(
    const uint32x4* __restrict__ A, const uint32x4* __restrict__ B,
    uint32x4* __restrict__ O, int row0, int n_rows)
{
    int i = row0 + blockIdx.x * BLOCK + threadIdx.x;
    if (i >= n_rows) return;
    uint32x4 o0, o1;
    fp8_add_row(A[2 * i], A[2 * i + 1], B[2 * i], B[2 * i + 1], o0, o1);
    __builtin_nontemporal_store(o0, &O[2 * i]);
    __builtin_nontemporal_store(o1, &O[2 * i + 1]);
}

extern "C" void kernel_launch(void* const* d_in, const int* in_sizes, int n_in,
                              void* d_out, int out_size, void* d_ws, size_t ws_size,
                              hipStream_t stream) {
    const uint32x4* A = (const uint32x4*)d_in[0];
    const uint32x4* B = (const uint32x4*)d_in[1];
    uint32x4* O = (uint32x4*)d_out;
    int n_rows = in_sizes[0] / 8;

    int full_blocks = n_rows / ROWS_PER_BLOCK;
    int done_rows = full_blocks * ROWS_PER_BLOCK;
    int rem = n_rows - done_rows;

    if (full_blocks > 0)
        fp8_adder_fast<<<full_blocks, BLOCK, 0, stream>>>(A, B, O);
    if (rem > 0) {
        int tail_blocks = (rem + BLOCK - 1) / BLOCK;
        fp8_adder_tail<<<tail_blocks, BLOCK, 0, stream>>>(A, B, O, done_rows, n_rows);
    }
}

// Round 5
// 299.784 us; speedup vs baseline: 1.0751x; 1.0751x over previous
//
#include <hip/hip_runtime.h>

// Gate-level FP8 E4M3 adder circuit, replayed as integer bit ops.
// Each row = 8 float32 "bits" (sign | exp4 | man3, MSB first), values in {0.0,1.0}.
// 1.0f == 0x3F800000 -> bit = (u >> 23) & 1. Output bit b -> b ? 0x3F800000 : 0.
//
// R4: controlled A/B vs R3 — branch-free structure kept, nontemporal LOADS
// restored (R2 with nt loads: 81 us @ 3.45 TB/s; R3 with plain loads: 129 us
// @ 2.2 TB/s; identical HBM bytes -> nt load policy is the suspect variable).

typedef unsigned int uint32x4 __attribute__((ext_vector_type(4)));

__device__ __forceinline__ unsigned bit_of(unsigned u) { return (u >> 23) & 1u; }
__device__ __forceinline__ unsigned f_of(unsigned b)   { return b ? 0x3F800000u : 0u; }

__device__ __forceinline__ void fp8_add_row(const uint32x4& a0, const uint32x4& a1,
                                            const uint32x4& b0, const uint32x4& b1,
                                            uint32x4& o0, uint32x4& o1)
{
    unsigned sa = bit_of(a0.x);
    unsigned ea = (bit_of(a0.y) << 3) | (bit_of(a0.z) << 2) | (bit_of(a0.w) << 1) | bit_of(a1.x);
    unsigned ma = (bit_of(a1.y) << 2) | (bit_of(a1.z) << 1) | bit_of(a1.w);
    unsigned sb = bit_of(b0.x);
    unsigned eb = (bit_of(b0.y) << 3) | (bit_of(b0.z) << 2) | (bit_of(b0.w) << 1) | bit_of(b1.x);
    unsigned mb = (bit_of(b1.y) << 2) | (bit_of(b1.z) << 1) | bit_of(b1.w);

    // comparator4 + OR(gt,eq): sel = (ea >= eb)
    unsigned sel = (ea >= eb) ? 1u : 0u;
    unsigned exp_l = sel ? ea : eb, exp_s = sel ? eb : ea;
    unsigned man_l = sel ? ma : mb, man_s = sel ? mb : ma;
    unsigned sign_l = sel ? sa : sb, sign_s = sel ? sb : sa;

    unsigned diff = (exp_l - exp_s) & 0xFu;        // 4-bit subtract, exact (l >= s)
    unsigned hid_l = exp_l ? 1u : 0u;
    unsigned hid_s = exp_s ? 1u : 0u;

    // 12-bit extended mantissas, MSB-first bit 11..0: [0, hid, man(3), 0*7]
    unsigned ext_l = (hid_l << 10) | (man_l << 7);
    unsigned ext_s = ((hid_s << 10) | (man_s << 7)) >> diff;

    unsigned same_sign = (sign_l == sign_s);
    // 12-bit ripple add/sub both wrap mod 4096 (carry/borrow-out dropped)
    unsigned mant = same_sign ? ((ext_l + ext_s) & 0xFFFu)
                              : ((ext_l - ext_s) & 0xFFFu);

    unsigned top8 = mant >> 4;                     // mant bits 11..4
    unsigned lzc = top8 ? (unsigned)(__clz((int)top8) - 24) : 7u;  // lzd8 -> 7 on zero
    unsigned norm = (top8 << lzc) & 0xFFu;         // barrel_left8

    unsigned exp_new = (exp_l - lzc + 1u) & 0xFu;  // subtract_bits + increment4, mod 16
    unsigned man_out = (norm >> 4) & 0x7u;         // norm[1:4] = bits 6..4

    o0.x = f_of(sign_l);
    o0.y = f_of((exp_new >> 3) & 1u);
    o0.z = f_of((exp_new >> 2) & 1u);
    o0.w = f_of((exp_new >> 1) & 1u);
    o1.x = f_of(exp_new & 1u);
    o1.y = f_of((man_out >> 2) & 1u);
    o1.z = f_of((man_out >> 1) & 1u);
    o1.w = f_of(man_out & 1u);
}

constexpr int RPT = 4;
constexpr int BLOCK = 256;
constexpr int ROWS_PER_BLOCK = BLOCK * RPT;

// Fast path: every row index in range by construction.
__global__ __launch_bounds__(BLOCK) void fp8_adder_fast(
    const uint32x4* __restrict__ A, const uint32x4* __restrict__ B,
    uint32x4* __restrict__ O)
{
    int base = blockIdx.x * ROWS_PER_BLOCK + threadIdx.x;

    uint32x4 a0[RPT], a1[RPT], b0[RPT], b1[RPT];
    #pragma unroll
    for (int k = 0; k < RPT; ++k) {
        int i = base + k * BLOCK;
        a0[k] = __builtin_nontemporal_load(&A[2 * i]);
        a1[k] = __builtin_nontemporal_load(&A[2 * i + 1]);
        b0[k] = __builtin_nontemporal_load(&B[2 * i]);
        b1[k] = __builtin_nontemporal_load(&B[2 * i + 1]);
    }

    #pragma unroll
    for (int k = 0; k < RPT; ++k) {
        int i = base + k * BLOCK;
        uint32x4 o0, o1;
        fp8_add_row(a0[k], a1[k], b0[k], b1[k], o0, o1);
        __builtin_nontemporal_store(o0, &O[2 * i]);
        __builtin_nontemporal_store(o1, &O[2 * i + 1]);
    }
}

// Tail: bounds-checked, one row per thread.
__global__ __launch_bounds__(BLOCK) void fp8_adder_tail(
    const uint32x4* __restrict__ A, const uint32x4* __restrict__ B,
    uint32x4* __restrict__ O, int row0, int n_rows)
{
    int i = row0 + blockIdx.x * BLOCK + threadIdx.x;
    if (i >= n_rows) return;
    uint32x4 a0 = __builtin_nontemporal_load(&A[2 * i]);
    uint32x4 a1 = __builtin_nontemporal_load(&A[2 * i + 1]);
    uint32x4 b0 = __builtin_nontemporal_load(&B[2 * i]);
    uint32x4 b1 = __builtin_nontemporal_load(&B[2 * i + 1]);
    uint32x4 o0, o1;
    fp8_add_row(a0, a1, b0, b1, o0, o1);
    __builtin_nontemporal_store(o0, &O[2 * i]);
    __builtin_nontemporal_store(o1, &O[2 * i + 1]);
}

extern "C" void kernel_launch(void* const* d_in, const int* in_sizes, int n_in,
                              void* d_out, int out_size, void* d_ws, size_t ws_size,
                              hipStream_t stream) {
    const uint32x4* A = (const uint32x4*)d_in[0];
    const uint32x4* B = (const uint32x4*)d_in[1];
    uint32x4* O = (uint32x4*)d_out;
    int n_rows = in_sizes[0] / 8;

    int full_blocks = n_rows / ROWS_PER_BLOCK;
    int done_rows = full_blocks * ROWS_PER_BLOCK;
    int rem = n_rows - done_rows;

    if (full_blocks > 0)
        fp8_adder_fast<<<full_blocks, BLOCK, 0, stream>>>(A, B, O);
    if (rem > 0) {
        int tail_blocks = (rem + BLOCK - 1) / BLOCK;
        fp8_adder_tail<<<tail_blocks, BLOCK, 0, stream>>>(A, B, O, done_rows, n_rows);
    }
}

// Round 6
// 293.589 us; speedup vs baseline: 1.0978x; 1.0211x over previous
//
#include <hip/hip_runtime.h>

// Gate-level FP8 E4M3 adder circuit, replayed as integer bit ops.
// Each row = 8 float32 "bits" (sign | exp4 | man3, MSB first), values in {0.0,1.0}.
// 1.0f == 0x3F800000 -> bit = (u >> 23) & 1. Output bit b -> b ? 0x3F800000 : 0.
//
// R5: all global VMEM instructions made unit-stride/full-cache-line.
// R4's pattern had lanes at 32 B stride per instruction (16 half-used lines
// per load, partial-line nt stores). Now: dense nt loads -> per-wave LDS
// buffer (XOR-swizzled, conflict-free) -> one row per lane -> results back
// through LDS -> dense nt stores. Intra-wave only, no barriers.

typedef unsigned int uint32x4 __attribute__((ext_vector_type(4)));

__device__ __forceinline__ unsigned bit_of(unsigned u) { return (u >> 23) & 1u; }
__device__ __forceinline__ unsigned f_of(unsigned b)   { return b ? 0x3F800000u : 0u; }

// Bijective self-inverse swizzle on 16B-slot index m in [0,128):
// XOR low 3 bits with bits 3..5. Dense (m=lane) and stride-2 (m=2*lane(+1))
// phases both give all-distinct bank classes within every 8-lane group.
__device__ __forceinline__ int swz(int m) { return m ^ ((m >> 3) & 7); }

__device__ __forceinline__ void fp8_add_row(const uint32x4& a0, const uint32x4& a1,
                                            const uint32x4& b0, const uint32x4& b1,
                                            uint32x4& o0, uint32x4& o1)
{
    unsigned sa = bit_of(a0.x);
    unsigned ea = (bit_of(a0.y) << 3) | (bit_of(a0.z) << 2) | (bit_of(a0.w) << 1) | bit_of(a1.x);
    unsigned ma = (bit_of(a1.y) << 2) | (bit_of(a1.z) << 1) | bit_of(a1.w);
    unsigned sb = bit_of(b0.x);
    unsigned eb = (bit_of(b0.y) << 3) | (bit_of(b0.z) << 2) | (bit_of(b0.w) << 1) | bit_of(b1.x);
    unsigned mb = (bit_of(b1.y) << 2) | (bit_of(b1.z) << 1) | bit_of(b1.w);

    // comparator4 + OR(gt,eq): sel = (ea >= eb)
    unsigned sel = (ea >= eb) ? 1u : 0u;
    unsigned exp_l = sel ? ea : eb, exp_s = sel ? eb : ea;
    unsigned man_l = sel ? ma : mb, man_s = sel ? mb : ma;
    unsigned sign_l = sel ? sa : sb, sign_s = sel ? sb : sa;

    unsigned diff = (exp_l - exp_s) & 0xFu;        // 4-bit subtract, exact (l >= s)
    unsigned hid_l = exp_l ? 1u : 0u;
    unsigned hid_s = exp_s ? 1u : 0u;

    // 12-bit extended mantissas, MSB-first bit 11..0: [0, hid, man(3), 0*7]
    unsigned ext_l = (hid_l << 10) | (man_l << 7);
    unsigned ext_s = ((hid_s << 10) | (man_s << 7)) >> diff;

    unsigned same_sign = (sign_l == sign_s);
    // 12-bit ripple add/sub both wrap mod 4096 (carry/borrow-out dropped)
    unsigned mant = same_sign ? ((ext_l + ext_s) & 0xFFFu)
                              : ((ext_l - ext_s) & 0xFFFu);

    unsigned top8 = mant >> 4;                     // mant bits 11..4
    unsigned lzc = top8 ? (unsigned)(__clz((int)top8) - 24) : 7u;  // lzd8 -> 7 on zero
    unsigned norm = (top8 << lzc) & 0xFFu;         // barrel_left8

    unsigned exp_new = (exp_l - lzc + 1u) & 0xFu;  // subtract_bits + increment4, mod 16
    unsigned man_out = (norm >> 4) & 0x7u;         // norm[1:4] = bits 6..4

    o0.x = f_of(sign_l);
    o0.y = f_of((exp_new >> 3) & 1u);
    o0.z = f_of((exp_new >> 2) & 1u);
    o0.w = f_of((exp_new >> 1) & 1u);
    o1.x = f_of(exp_new & 1u);
    o1.y = f_of((man_out >> 2) & 1u);
    o1.z = f_of((man_out >> 1) & 1u);
    o1.w = f_of(man_out & 1u);
}

constexpr int RPT = 4;            // rounds per wave (64 rows each)
constexpr int BLOCK = 256;
constexpr int WAVES = BLOCK / 64;
constexpr int ROWS_PER_BLOCK = BLOCK * RPT;  // 1024

__global__ __launch_bounds__(BLOCK) void fp8_adder_fast(
    const uint32x4* __restrict__ A, const uint32x4* __restrict__ B,
    uint32x4* __restrict__ O)
{
    // Per-wave: 256 slots of 16B -> A words [0,128), B words [128,256).
    __shared__ uint32x4 sh[WAVES * 256];

    int lane = threadIdx.x & 63;
    int w = threadIdx.x >> 6;
    uint32x4* shW = &sh[w * 256];

    int rowBase = blockIdx.x * ROWS_PER_BLOCK + w * (64 * RPT);

    #pragma unroll
    for (int k = 0; k < RPT; ++k) {
        int WW = 2 * (rowBase + k * 64);   // word index of first A/B word this round

        // Dense, full-line nt loads: lane l gets word WW+l and WW+64+l.
        uint32x4 vA0 = __builtin_nontemporal_load(&A[WW + lane]);
        uint32x4 vA1 = __builtin_nontemporal_load(&A[WW + 64 + lane]);
        uint32x4 vB0 = __builtin_nontemporal_load(&B[WW + lane]);
        uint32x4 vB1 = __builtin_nontemporal_load(&B[WW + 64 + lane]);

        // Stage word m at slot swz(m) (intra-wave, no barrier needed).
        shW[swz(lane)]            = vA0;
        shW[swz(64 + lane)]       = vA1;
        shW[128 + swz(lane)]      = vB0;
        shW[128 + swz(64 + lane)] = vB1;

        // Lane l owns row rowBase + k*64 + l -> words 2l, 2l+1.
        uint32x4 a0 = shW[swz(2 * lane)];
        uint32x4 a1 = shW[swz(2 * lane + 1)];
        uint32x4 b0 = shW[128 + swz(2 * lane)];
        uint32x4 b1 = shW[128 + swz(2 * lane + 1)];

        uint32x4 o0, o1;
        fp8_add_row(a0, a1, b0, b1, o0, o1);

        // Deposit results (reuse A region), read back dense, store full-line.
        shW[swz(2 * lane)]     = o0;
        shW[swz(2 * lane + 1)] = o1;

        uint32x4 w0 = shW[swz(lane)];
        uint32x4 w1 = shW[swz(64 + lane)];
        __builtin_nontemporal_store(w0, &O[WW + lane]);
        __builtin_nontemporal_store(w1, &O[WW + 64 + lane]);
    }
}

// Tail: bounds-checked, one row per thread (general-case safety net).
__global__ __launch_bounds__(BLOCK) void fp8_adder_tail(
    const uint32x4* __restrict__ A, const uint32x4* __restrict__ B,
    uint32x4* __restrict__ O, int row0, int n_rows)
{
    int i = row0 + blockIdx.x * BLOCK + threadIdx.x;
    if (i >= n_rows) return;
    uint32x4 a0 = __builtin_nontemporal_load(&A[2 * i]);
    uint32x4 a1 = __builtin_nontemporal_load(&A[2 * i + 1]);
    uint32x4 b0 = __builtin_nontemporal_load(&B[2 * i]);
    uint32x4 b1 = __builtin_nontemporal_load(&B[2 * i + 1]);
    uint32x4 o0, o1;
    fp8_add_row(a0, a1, b0, b1, o0, o1);
    __builtin_nontemporal_store(o0, &O[2 * i]);
    __builtin_nontemporal_store(o1, &O[2 * i + 1]);
}

extern "C" void kernel_launch(void* const* d_in, const int* in_sizes, int n_in,
                              void* d_out, int out_size, void* d_ws, size_t ws_size,
                              hipStream_t stream) {
    const uint32x4* A = (const uint32x4*)d_in[0];
    const uint32x4* B = (const uint32x4*)d_in[1];
    uint32x4* O = (uint32x4*)d_out;
    int n_rows = in_sizes[0] / 8;

    int full_blocks = n_rows / ROWS_PER_BLOCK;
    int done_rows = full_blocks * ROWS_PER_BLOCK;
    int rem = n_rows - done_rows;

    if (full_blocks > 0)
        fp8_adder_fast<<<full_blocks, BLOCK, 0, stream>>>(A, B, O);
    if (rem > 0) {
        int tail_blocks = (rem + BLOCK - 1) / BLOCK;
        fp8_adder_tail<<<tail_blocks, BLOCK, 0, stream>>>(A, B, O, done_rows, n_rows);
    }
}